// Round 11
// baseline (219.199 us; speedup 1.0000x reference)
//
#include <hip/hip_runtime.h>
#include <stdint.h>

// CutOutput: per visit v (8192), stable descending argsort of D=1571 f32
// scores; emit index order, zeroing ranks >= L = base[v].
//
// key32 = ~orderable(f): ascending key == descending f32 (mapping proven
// end-to-end in rounds 2-10). NEW: sort only the TOP 16 key bits by radix
// (2 passes x 8-bit ballot radix, round-10-proven code), moving a single
// packed word pk = (key & 0xFFFF0000) | idx. Low key halves stay put in
// lowb[idx]. Equal-top16 runs (E ~ 19 pairs/visit) are then fixed up with a
// tiny stable insertion sort comparing (lowb[idx] << 16) | idx == full-key
// order + index tie-break. LSD stability in the 2 passes keeps index order
// within equal top16, so fixup input order is index-ascending and the
// stable insertion sort reproduces JAX's argsort(-x) exactly.
//
// Sentinels (p >= D) use top16 = 0xFFFF, impossible for real keys (would
// need a negative NaN): they sort strictly last and are skipped by fixup.
// Fixup run detection reads only top16 fields; in-run permutation never
// changes any top16 -> concurrent detection/sorting is race-benign, and
// distinct runs are disjoint ranges.

#define BLK 256

template<int RCT>
__device__ __forceinline__ void rank_scan_scatter(
    uint32_t* __restrict__ hist, uint32_t* __restrict__ sbuf,
    uint32_t* __restrict__ kout,
    const uint32_t (&pk)[RCT], const uint32_t (&dig)[RCT],
    const int t, const int lane, const int w, const uint64_t lt) {
  // Rank within wave: ballot digit-match; leader bumps running count.
  // (verbatim round-10 structure; o processed ascending -> stable in p order)
  uint32_t rnk[RCT];
#pragma unroll
  for (int o = 0; o < RCT; ++o) {
    uint64_t mm = ~0ull;
#pragma unroll
    for (int b = 0; b < 8; ++b) {
      const uint32_t bit = (dig[o] >> b) & 1u;
      const uint64_t bb  = __ballot(bit);
      mm &= bit ? bb : ~bb;
    }
    const uint32_t before = (uint32_t)__popcll(mm & lt);
    const uint32_t cnt    = (uint32_t)__popcll(mm);
    const uint32_t b0     = hist[w * 256 + dig[o]];
    if (before == 0) hist[w * 256 + dig[o]] = b0 + cnt;  // leader updates
    rnk[o] = b0 + before;
  }
  __syncthreads();

  // Block scan of 256 digit totals (round-10 verbatim).
  sbuf[t] = hist[0 * 256 + t] + hist[1 * 256 + t] +
            hist[2 * 256 + t] + hist[3 * 256 + t];
  __syncthreads();
  if (t < 64) {
    const uint32_t c0 = sbuf[4 * t + 0], c1 = sbuf[4 * t + 1];
    const uint32_t c2 = sbuf[4 * t + 2], c3 = sbuf[4 * t + 3];
    const uint32_t s  = c0 + c1 + c2 + c3;
    uint32_t vs = s;
#pragma unroll
    for (int d = 1; d < 64; d <<= 1) {
      const uint32_t u2 = __shfl_up(vs, d, 64);
      if (lane >= d) vs += u2;
    }
    const uint32_t ex = vs - s;
    sbuf[4 * t + 0] = ex;
    sbuf[4 * t + 1] = ex + c0;
    sbuf[4 * t + 2] = ex + c0 + c1;
    sbuf[4 * t + 3] = ex + c0 + c1 + c2;
  }
  __syncthreads();
  {
    const uint32_t c0 = hist[0 * 256 + t], c1 = hist[1 * 256 + t];
    const uint32_t c2 = hist[2 * 256 + t];
    uint32_t run = sbuf[t];
    hist[0 * 256 + t] = run; run += c0;
    hist[1 * 256 + t] = run; run += c1;
    hist[2 * 256 + t] = run; run += c2;
    hist[3 * 256 + t] = run;
  }
  __syncthreads();

  // Scatter (stable).
#pragma unroll
  for (int o = 0; o < RCT; ++o)
    kout[hist[w * 256 + dig[o]] + rnk[o]] = pk[o];
}

template<int RCT>
__global__ __launch_bounds__(BLK, 6) void cutout_radix16(
    const float* __restrict__ to_cut,
    const int*  __restrict__ base,
    int*        __restrict__ out,
    int D) {
  constexpr int MCT = RCT * 256;   // sort length (1792 for D=1571)
  constexpr int WSH = RCT * 64;    // elements per wave
  __shared__ uint32_t kA[MCT];     // final buffer
  __shared__ uint32_t kB[MCT];     // intermediate
  __shared__ uint16_t lowb[MCT];   // low16 of key, indexed by ORIGINAL idx
  __shared__ uint32_t hist[4 * 256];
  __shared__ uint32_t sbuf[256];

  const int      t    = threadIdx.x;
  const int      lane = t & 63;
  const int      w    = t >> 6;
  const int      v    = blockIdx.x;
  const size_t   off  = (size_t)v * (size_t)D;
  const uint64_t lt   = (1ull << lane) - 1;

  // ---- Pass A (digit = key bits 16..23): load DIRECTLY from global in
  //      wave-position order p (coalesced: 64 consecutive lanes).
#pragma unroll
  for (int q = 0; q < 4; ++q) hist[q * 256 + t] = 0;
  __syncthreads();

  uint32_t pk[RCT], dig[RCT];
#pragma unroll
  for (int o = 0; o < RCT; ++o) {
    const int p = w * WSH + o * 64 + lane;
    uint32_t packed = 0xFFFF0000u | (uint32_t)p;      // sentinel (p >= D)
    if (p < D) {
      uint32_t u = __float_as_uint(to_cut[off + p]);
      u = (u & 0x80000000u) ? ~u : (u | 0x80000000u); // ascending-orderable
      const uint32_t key = ~u;                        // ascending == desc f32
      packed = (key & 0xFFFF0000u) | (uint32_t)p;
      lowb[p] = (uint16_t)(key & 0xFFFFu);
    }
    pk[o]  = packed;
    dig[o] = (packed >> 16) & 255u;
  }
  rank_scan_scatter<RCT>(hist, sbuf, kB, pk, dig, t, lane, w, lt);
  __syncthreads();

  // ---- Pass B (digit = key bits 24..31): gather kB in p order.
#pragma unroll
  for (int q = 0; q < 4; ++q) hist[q * 256 + t] = 0;
  __syncthreads();
#pragma unroll
  for (int o = 0; o < RCT; ++o) {
    const int p = w * WSH + o * 64 + lane;
    pk[o]  = kB[p];
    dig[o] = pk[o] >> 24;
  }
  rank_scan_scatter<RCT>(hist, sbuf, kA, pk, dig, t, lane, w, lt);
  __syncthreads();

  // ---- Fixup: stable insertion sort of equal-top16 runs by
  //      (lowb[idx] << 16) | idx  == full-key order + index tie-break.
  //      Run-start owner sorts the whole run; detection reads only top16.
#pragma unroll
  for (int o = 0; o < RCT; ++o) {
    const int r = o * BLK + t;
    const uint32_t k16 = kA[r] >> 16;
    if (k16 == 0xFFFFu) continue;                     // sentinel region
    if (r + 1 >= MCT || (kA[r + 1] >> 16) != k16) continue;  // run len < 2
    if (r > 0 && (kA[r - 1] >> 16) == k16) continue;  // not the start
    int e = r + 2;
    while (e < MCT && (kA[e] >> 16) == k16) ++e;
    for (int i = r + 1; i < e; ++i) {
      const uint32_t wi = kA[i];
      const uint32_t ci = ((uint32_t)lowb[wi & 0xFFFFu] << 16) | (wi & 0xFFFFu);
      int j = i - 1;
      while (j >= r) {
        const uint32_t wj = kA[j];
        const uint32_t cj = ((uint32_t)lowb[wj & 0xFFFFu] << 16) | (wj & 0xFFFFu);
        if (cj <= ci) break;
        kA[j + 1] = wj;
        --j;
      }
      kA[j + 1] = wi;
    }
  }
  __syncthreads();

  // ---- Emit: rank r -> original index (low half of packed), 0 for r >= L.
  const int L = base[v];
#pragma unroll
  for (int o = 0; o < RCT; ++o) {
    const int r = o * BLK + t;
    if (r < D) out[off + r] = (r < L) ? (int)(kA[r] & 0xFFFFu) : 0;
  }
}

extern "C" void kernel_launch(void* const* d_in, const int* in_sizes, int n_in,
                              void* d_out, int out_size, void* d_ws, size_t ws_size,
                              hipStream_t stream) {
  const float* to_cut = (const float*)d_in[0];
  const int*   base   = (const int*)d_in[1];
  // ids = repeat(arange(P), T) sorted -> lens[flat v] == base[v]; no segment pass.
  const int N = in_sizes[1];      // visits (P*T)
  const int D = in_sizes[0] / N;  // codes per visit (1571 -> R=7)

  int* outp = (int*)d_out;
  const int R = ((D + 255) & ~255) >> 8;
  switch (R) {
    case 1: cutout_radix16<1><<<dim3(N), dim3(BLK), 0, stream>>>(to_cut, base, outp, D); break;
    case 2: cutout_radix16<2><<<dim3(N), dim3(BLK), 0, stream>>>(to_cut, base, outp, D); break;
    case 3: cutout_radix16<3><<<dim3(N), dim3(BLK), 0, stream>>>(to_cut, base, outp, D); break;
    case 4: cutout_radix16<4><<<dim3(N), dim3(BLK), 0, stream>>>(to_cut, base, outp, D); break;
    case 5: cutout_radix16<5><<<dim3(N), dim3(BLK), 0, stream>>>(to_cut, base, outp, D); break;
    case 6: cutout_radix16<6><<<dim3(N), dim3(BLK), 0, stream>>>(to_cut, base, outp, D); break;
    case 7: cutout_radix16<7><<<dim3(N), dim3(BLK), 0, stream>>>(to_cut, base, outp, D); break;
    default: cutout_radix16<8><<<dim3(N), dim3(BLK), 0, stream>>>(to_cut, base, outp, D); break;
  }
}